// Round 14
// baseline (111.388 us; speedup 1.0000x reference)
//
#include <hip/hip_runtime.h>
#include <hip/hip_bf16.h>

typedef unsigned short ushort_t;
typedef unsigned int uint_t;
typedef __attribute__((ext_vector_type(8))) short short8;
typedef __attribute__((ext_vector_type(4))) float f32x4;
typedef __attribute__((ext_vector_type(2))) uint_t uint2_t;

#define FOLD 128
// exp(COEFF*x^2) = 2^(-(x*S)^2);  S = sqrt(0.5/ln2)/DELTA, DELTA = 30/63
#define S_CONST 1.78357580f
#define DS_CONST 0.84932180f   /* DELTA * S_CONST = sqrt(0.5/ln2) */

__device__ __forceinline__ uint_t pkbf(float a, float b) {
    // dword = bf16(b)<<16 | bf16(a), RNE via v_cvt_pk_bf16_f32
    __hip_bfloat162 h2 = __float22bfloat162_rn(float2{a, b});
    uint_t u;
    __builtin_memcpy(&u, &h2, sizeof(u));
    return u;
}

#define NWAVES 8
// dword offsets in dynamic LDS (total 37120 dwords = 145 KB)
#define W1_OFF 0        /* 20480 dw: W1 bf16 fragment-packed */
#define W2_OFF 20480    /*  8192 dw: W2 bf16 fragment-packed */
#define B1_OFF 28672    /*   128 dw fp32 */
#define B2_OFF 28800    /*   128 dw fp32 */
#define H_OFF  28928    /*  8 waves x 1024 dw h-scratch */
#define LDS_DW 37120

// Barrier-free wave-autonomous kernel: one W-staging barrier, then each wave
// processes 32-edge tiles fully independently (no block sync in the loop).
__global__ __launch_bounds__(512) void fused(
    const float* __restrict__ lig,
    const float* __restrict__ p0, const float* __restrict__ p1,
    const float* __restrict__ p2, const float* __restrict__ p3,
    const float* __restrict__ p4,
    const float* __restrict__ W1, const float* __restrict__ W2,
    const float* __restrict__ b1, const float* __restrict__ b2,
    const int* __restrict__ src, const int* __restrict__ dst,
    float* __restrict__ out, int E)
{
    extern __shared__ uint_t smem[];
    uint_t* W1L = smem + W1_OFF;
    uint_t* W2L = smem + W2_OFF;
    const float* b1L = (const float*)(smem + B1_OFF);
    const float* b2L = (const float*)(smem + B2_OFF);

    const int t = threadIdx.x;
    const int w = t >> 6;
    const int l = t & 63;
    const int eL = l & 15, g = l >> 4;
    uint_t* hw = smem + H_OFF + (w << 10);   // 4 KB private scratch per wave

    // ---- Stage W1/W2 (bf16 fragment order) + biases into LDS, once ----
    // frag dword idx = ((ks*8+nt)*64 + l2)*4 + jj  <->  elems j=2jj,2jj+1:
    //   W[ks*32 + (l2>>4)*8 + j][nt*16 + (l2&15)]
    for (int idx = t; idx < 20480; idx += 512) {
        int jj = idx & 3, l2 = (idx >> 2) & 63, nt = (idx >> 8) & 7, ks = idx >> 11;
        int row = ks * 32 + ((l2 >> 4) << 3) + 2 * jj;
        int col = nt * 16 + (l2 & 15);
        W1L[idx] = pkbf(W1[row * FOLD + col], W1[(row + 1) * FOLD + col]);
    }
    for (int idx = t; idx < 8192; idx += 512) {
        int jj = idx & 3, l2 = (idx >> 2) & 63, nt = (idx >> 8) & 7, ks = idx >> 11;
        int row = ks * 32 + ((l2 >> 4) << 3) + 2 * jj;
        int col = nt * 16 + (l2 & 15);
        W2L[idx] = pkbf(W2[row * FOLD + col], W2[(row + 1) * FOLD + col]);
    }
    if (t < 128) ((float*)(smem + B1_OFF))[t] = b1[t];
    else if (t < 256) ((float*)(smem + B2_OFF))[t - 128] = b2[t - 128];
    __syncthreads();   // the ONLY block barrier

    const int NT = (E + 31) >> 5;
    const int stride = gridDim.x * NWAVES;
    int wt = blockIdx.x * NWAVES + w;
    if (wt >= NT) return;

    // lane's gather duty: channel g (0..3) via GP; lanes g==0 also do channel 4 (p4)
    const float* GP = (g == 0) ? p0 : (g == 1) ? p1 : (g == 2) ? p2 : p3;
    const bool g0 = (g == 0);
    const float gbase = (float)(8 * g) * DS_CONST;

    // ---- Prologue: idx + pos loads for first tile (both edge halves) ----
    float Ax[2], Ay[2], Az[2], Px[2], Py[2], Pz[2], Qx[2], Qy[2], Qz[2];
    {
        #pragma unroll
        for (int eh = 0; eh < 2; ++eh) {
            int e = wt * 32 + eh * 16 + eL; if (e >= E) e = E - 1;
            int s = src[e], d2 = dst[e];
            Ax[eh] = lig[3 * s]; Ay[eh] = lig[3 * s + 1]; Az[eh] = lig[3 * s + 2];
            Px[eh] = GP[3 * d2]; Py[eh] = GP[3 * d2 + 1]; Pz[eh] = GP[3 * d2 + 2];
            if (g0) { Qx[eh] = p4[3 * d2]; Qy[eh] = p4[3 * d2 + 1]; Qz[eh] = p4[3 * d2 + 2]; }
        }
    }

    while (true) {
        const int wt2 = wt + stride;
        const bool more = (wt2 < NT);

        // ---- Issue next tile's src/dst loads ----
        int sB[2], dB[2];
        if (more) {
            #pragma unroll
            for (int eh = 0; eh < 2; ++eh) {
                int e = wt2 * 32 + eh * 16 + eL; if (e >= E) e = E - 1;
                sB[eh] = src[e]; dB[eh] = dst[e];
            }
        }

        // ---- Distances + cross-lane redistribution (wave-local shuffles) ----
        float u00[5][2];
        #pragma unroll
        for (int eh = 0; eh < 2; ++eh) {
            float dx = Ax[eh] - Px[eh], dy = Ay[eh] - Py[eh], dz = Az[eh] - Pz[eh];
            float dm = sqrtf(dx * dx + dy * dy + dz * dz);   // channel g of edge eL
            float d4 = 0.f;
            if (g0) {
                float ex = Ax[eh] - Qx[eh], ey = Ay[eh] - Qy[eh], ez = Az[eh] - Qz[eh];
                d4 = sqrtf(ex * ex + ey * ey + ez * ez);
            }
            #pragma unroll
            for (int c = 0; c < 4; ++c)
                u00[c][eh] = __builtin_fmaf(__shfl(dm, c * 16 + eL), S_CONST, -gbase);
            u00[4][eh] = __builtin_fmaf(__shfl(d4, eL), S_CONST, -gbase);
        }

        // ---- RBF expansion into register B-fragments a[eh][ks] ----
        short8 a[2][10];
        #pragma unroll
        for (int ks = 0; ks < 10; ++ks) {
            const int c = ks >> 1;
            #pragma unroll
            for (int eh = 0; eh < 2; ++eh) {
                uint_t dwv[4];
                #pragma unroll
                for (int jj = 0; jj < 4; ++jj) {
                    float k0 = (float)((ks & 1) * 32 + 2 * jj) * DS_CONST;
                    float k1 = (float)((ks & 1) * 32 + 2 * jj + 1) * DS_CONST;
                    float ua = u00[c][eh] - k0;
                    float ub = u00[c][eh] - k1;
                    float va = __builtin_amdgcn_exp2f(-(ua * ua));
                    float vb = __builtin_amdgcn_exp2f(-(ub * ub));
                    dwv[jj] = pkbf(va, vb);
                }
                __builtin_memcpy(&a[eh][ks], dwv, 16);
            }
        }

        // ---- Issue next tile's position loads (indices arrived during exp) ----
        float Bx[2], By[2], Bz[2], Rx[2], Ry[2], Rz[2], Sx[2], Sy[2], Sz[2];
        if (more) {
            #pragma unroll
            for (int eh = 0; eh < 2; ++eh) {
                Bx[eh] = lig[3 * sB[eh]]; By[eh] = lig[3 * sB[eh] + 1]; Bz[eh] = lig[3 * sB[eh] + 2];
                Rx[eh] = GP[3 * dB[eh]]; Ry[eh] = GP[3 * dB[eh] + 1]; Rz[eh] = GP[3 * dB[eh] + 2];
                if (g0) { Sx[eh] = p4[3 * dB[eh]]; Sy[eh] = p4[3 * dB[eh] + 1]; Sz[eh] = p4[3 * dB[eh] + 2]; }
            }
        }

        // ---- GEMM1: acc1[nt][eh] = (W1^T-chunk)·attr; each W-frag read once ----
        f32x4 acc1[8][2];
        #pragma unroll
        for (int nt = 0; nt < 8; ++nt)
            #pragma unroll
            for (int eh = 0; eh < 2; ++eh) acc1[nt][eh] = f32x4{0.f, 0.f, 0.f, 0.f};
        __builtin_amdgcn_s_setprio(1);
        #pragma unroll
        for (int ks = 0; ks < 10; ++ks) {
            #pragma unroll
            for (int nt = 0; nt < 8; ++nt) {
                const short8 wf = *reinterpret_cast<const short8*>(&W1L[((ks * 8 + nt) * 64 + l) * 4]);
                acc1[nt][0] = __builtin_amdgcn_mfma_f32_16x16x32_bf16(wf, a[0][ks], acc1[nt][0], 0, 0, 0);
                acc1[nt][1] = __builtin_amdgcn_mfma_f32_16x16x32_bf16(wf, a[1][ks], acc1[nt][1], 0, 0, 0);
            }
        }
        __builtin_amdgcn_s_setprio(0);

        // ---- GEMM2 with W2-fragment sharing across eh; two k-half phases ----
        // scratch layout: hw[eh*512 + eL*32 + k2l*16 + idx16^swz2]
        //   idx16 = (nt&1)*8 + g*2 + p  (write)  ==  g_t*4 + m (read), ks2 = nt>>1
        const int swz2 = (eL & 3) << 2;
        f32x4 acc2[8][2];
        #pragma unroll
        for (int nt = 0; nt < 8; ++nt)
            #pragma unroll
            for (int eh = 0; eh < 2; ++eh) acc2[nt][eh] = f32x4{0.f, 0.f, 0.f, 0.f};

        #pragma unroll
        for (int kh = 0; kh < 2; ++kh) {
            // pack h for nt = kh*4 .. kh*4+3, BOTH eh, into the 4 KB scratch
            #pragma unroll
            for (int nn = 0; nn < 4; ++nn) {
                const int nt = kh * 4 + nn;
                f32x4 bv = *reinterpret_cast<const f32x4*>(&b1L[nt * 16 + g * 4]);
                const int k2l = nn >> 1;
                const int idx16 = (((nt & 1) * 8 + g * 2) ^ swz2);
                #pragma unroll
                for (int eh = 0; eh < 2; ++eh) {
                    float v0 = fmaxf(acc1[nt][eh][0] + bv[0], 0.f);
                    float v1 = fmaxf(acc1[nt][eh][1] + bv[1], 0.f);
                    float v2 = fmaxf(acc1[nt][eh][2] + bv[2], 0.f);
                    float v3 = fmaxf(acc1[nt][eh][3] + bv[3], 0.f);
                    uint2_t pv;
                    pv[0] = pkbf(v0, v1);
                    pv[1] = pkbf(v2, v3);
                    *reinterpret_cast<uint2_t*>(&hw[eh * 512 + eL * 32 + k2l * 16 + idx16]) = pv;
                }
            }
            asm volatile("s_waitcnt lgkmcnt(0)" ::: "memory");
            // GEMM2 partial: global ks2 = kh*2 + k2l; wf2 read ONCE for both eh
            __builtin_amdgcn_s_setprio(1);
            #pragma unroll
            for (int k2l = 0; k2l < 2; ++k2l) {
                const int ks2 = kh * 2 + k2l;
                const int ridx = (g * 4) ^ swz2;
                const short8 hf0 = *reinterpret_cast<const short8*>(&hw[eL * 32 + k2l * 16 + ridx]);
                const short8 hf1 = *reinterpret_cast<const short8*>(&hw[512 + eL * 32 + k2l * 16 + ridx]);
                #pragma unroll
                for (int nt = 0; nt < 8; ++nt) {
                    const short8 wf2 = *reinterpret_cast<const short8*>(&W2L[((ks2 * 8 + nt) * 64 + l) * 4]);
                    acc2[nt][0] = __builtin_amdgcn_mfma_f32_16x16x32_bf16(wf2, hf0, acc2[nt][0], 0, 0, 0);
                    acc2[nt][1] = __builtin_amdgcn_mfma_f32_16x16x32_bf16(wf2, hf1, acc2[nt][1], 0, 0, 0);
                }
            }
            __builtin_amdgcn_s_setprio(0);
            asm volatile("s_waitcnt lgkmcnt(0)" ::: "memory");  // reads done before next kh overwrites
        }

        // ---- Stores (both eh) ----
        #pragma unroll
        for (int eh = 0; eh < 2; ++eh) {
            int e = wt * 32 + eh * 16 + eL;
            if (e < E) {
                #pragma unroll
                for (int nt = 0; nt < 8; ++nt) {
                    f32x4 bv2 = *reinterpret_cast<const f32x4*>(&b2L[nt * 16 + g * 4]);
                    f32x4 v = acc2[nt][eh] + bv2;
                    __builtin_nontemporal_store(v,
                        reinterpret_cast<f32x4*>(&out[(size_t)e * FOLD + nt * 16 + g * 4]));
                }
            }
        }

        if (!more) break;
        wt = wt2;
        #pragma unroll
        for (int eh = 0; eh < 2; ++eh) {
            Ax[eh] = Bx[eh]; Ay[eh] = By[eh]; Az[eh] = Bz[eh];
            Px[eh] = Rx[eh]; Py[eh] = Ry[eh]; Pz[eh] = Rz[eh];
            if (g0) { Qx[eh] = Sx[eh]; Qy[eh] = Sy[eh]; Qz[eh] = Sz[eh]; }
        }
    }
}

extern "C" void kernel_launch(void* const* d_in, const int* in_sizes, int n_in,
                              void* d_out, int out_size, void* d_ws, size_t ws_size,
                              hipStream_t stream) {
    const float* lig = (const float*)d_in[0];
    const float* p0  = (const float*)d_in[1];
    const float* p1  = (const float*)d_in[2];
    const float* p2  = (const float*)d_in[3];
    const float* p3  = (const float*)d_in[4];
    const float* p4  = (const float*)d_in[5];
    const float* W1  = (const float*)d_in[6];
    const float* b1  = (const float*)d_in[7];
    const float* W2  = (const float*)d_in[8];
    const float* b2  = (const float*)d_in[9];
    const int* src   = (const int*)d_in[10];
    const int* dst   = (const int*)d_in[11];
    float* out = (float*)d_out;
    const int E = in_sizes[10];

    hipFuncSetAttribute(reinterpret_cast<const void*>(fused),
                        hipFuncAttributeMaxDynamicSharedMemorySize, LDS_DW * 4);

    int nblk = 256;   // 1 block/CU (145 KB LDS); 8 autonomous waves per block
    fused<<<nblk, 512, LDS_DW * 4, stream>>>(lig, p0, p1, p2, p3, p4, W1, W2,
                                             b1, b2, src, dst, out, E);
}